// Round 5
// baseline (357.306 us; speedup 1.0000x reference)
//
#include <hip/hip_runtime.h>

#define N_NODES 50000
#define N_EDGES 800000
#define SCAN_BLOCKS 196              // ceil(50000/256)
#define SENTINEL 50000               // zero-row index in gather tables
#define PAD_CAP (N_EDGES + 7 * N_NODES + 32)  // padded slots + slack for over-read
#define NB 782                       // buckets of 64 nodes: ceil(50000/64)
#define BCAP 1536                    // slots per bucket (mean 1023, 16 sigma safe)
#define REGION_MAX 2048              // max padded u16 region per bucket

// ---------------- phase A: degree count + bucket scatter ----------------
__global__ void placeA_kernel(const int* __restrict__ edge_src,
                              const int* __restrict__ edge_dst,
                              int* __restrict__ deg,
                              int* __restrict__ bcnt,
                              unsigned int* __restrict__ bucket_buf) {
    int e = blockIdx.x * blockDim.x + threadIdx.x;
    if (e >= N_EDGES) return;
    int d = edge_dst[e];
    int s = edge_src[e];
    atomicAdd(&deg[d], 1);
    int b = d >> 6;
    int pos = atomicAdd(&bcnt[b], 1);
    bucket_buf[b * BCAP + pos] = (unsigned int)s | ((unsigned int)(d & 63) << 16);
}

// ---------------- scan step 1: per-block exclusive scan of PADDED deg ----------------
__global__ void scan1_kernel(const int* __restrict__ deg,
                             int* __restrict__ prs,
                             int* __restrict__ partials) {
    __shared__ int sm[256];
    int tid = threadIdx.x;
    int i = blockIdx.x * 256 + tid;
    int v = (i < N_NODES) ? ((deg[i] + 7) & ~7) : 0;   // pad to multiple of 8
    sm[tid] = v;
    __syncthreads();
    int x = v;
    for (int off = 1; off < 256; off <<= 1) {
        int y = (tid >= off) ? sm[tid - off] : 0;
        __syncthreads();
        x += y;
        sm[tid] = x;
        __syncthreads();
    }
    if (i < N_NODES) prs[i] = x - v;       // exclusive
    if (tid == 255) partials[blockIdx.x] = x;
}

// ---------------- scan step 2: scan block totals (1 block) ----------------
__global__ void scan2_kernel(int* __restrict__ partials) {
    __shared__ int sm[256];
    int tid = threadIdx.x;
    int v = (tid < SCAN_BLOCKS) ? partials[tid] : 0;
    sm[tid] = v;
    __syncthreads();
    int x = v;
    for (int off = 1; off < 256; off <<= 1) {
        int y = (tid >= off) ? sm[tid - off] : 0;
        __syncthreads();
        x += y;
        sm[tid] = x;
        __syncthreads();
    }
    if (tid < SCAN_BLOCKS) partials[tid] = x - v;
}

// ---------------- scan step 3: finalize prs, inv_deg ----------------
__global__ void scan3_kernel(int* __restrict__ prs,
                             const int* __restrict__ partials,
                             const int* __restrict__ deg,
                             float* __restrict__ inv_deg) {
    int i = blockIdx.x * blockDim.x + threadIdx.x;
    if (i < N_NODES) {
        int rs = prs[i] + partials[i >> 8];
        prs[i] = rs;
        int d = deg[i];
        inv_deg[i] = 1.0f / (float)max(d, 1);
        if (i == N_NODES - 1) prs[N_NODES] = rs + ((d + 7) & ~7);
    }
}

// ---------------- phase B: per-bucket place + coalesced flush ----------------
__global__ void placeB_kernel(const unsigned int* __restrict__ bucket_buf,
                              const int* __restrict__ bcnt,
                              const int* __restrict__ prs,
                              unsigned short* __restrict__ sorted_src) {
    __shared__ int cur[64];
    __shared__ unsigned short stage[REGION_MAX];
    int b = blockIdx.x;
    int n0 = b << 6;
    int nn = min(64, N_NODES - n0);
    int tid = threadIdx.x;
    int base = prs[n0];
    int rend = prs[n0 + nn];
    if (tid < nn) cur[tid] = prs[n0 + tid] - base;
    __syncthreads();
    int cnt = bcnt[b];
    for (int r = tid; r < cnt; r += 256) {
        unsigned int rec = bucket_buf[b * BCAP + r];
        int dl = rec >> 16;
        int pos = atomicAdd(&cur[dl], 1);
        stage[pos] = (unsigned short)(rec & 0xffffu);
    }
    __syncthreads();
    int region4 = (rend - base) >> 2;  // region is multiple of 8 u16s
    const uint2* st2 = reinterpret_cast<const uint2*>(stage);
    uint2* out2 = reinterpret_cast<uint2*>(sorted_src + base);
    for (int i = tid; i < region4; i += 256) out2[i] = st2[i];
}

// ---------------- bf16x2 pack (RNE) ----------------
__device__ __forceinline__ unsigned int pack_bf16x2(float x, float y) {
    unsigned int bx = __float_as_uint(x);
    unsigned int by = __float_as_uint(y);
    bx = (bx + 0x7fffu + ((bx >> 16) & 1u)) >> 16;
    by = (by + 0x7fffu + ((by >> 16) & 1u)) & 0xffff0000u;
    return (bx & 0xffffu) | by;
}

// ---------------- convert h -> bf16x2; zero sentinel rows ----------------
__global__ void convert_kernel(const float* __restrict__ h,
                               unsigned int* __restrict__ hb,
                               unsigned int* __restrict__ u1b,
                               unsigned int* __restrict__ u2b) {
    int idx = blockIdx.x * blockDim.x + threadIdx.x;  // over (N+1)*64
    if (idx >= (N_NODES + 1) * 64) return;
    if ((idx >> 6) == N_NODES) {
        hb[idx] = 0u;
        u1b[idx] = 0u;
        u2b[idx] = 0u;
    } else {
        float2 v = reinterpret_cast<const float2*>(h)[idx];
        hb[idx] = pack_bf16x2(v.x, v.y);
    }
}

// ---------------- pure gather layer: u_out = M * src (bf16 -> bf16) ----------------
// One wave per node; 4 groups x 16 lanes. 16 slots per iteration -> 4 uint4
// gathers in flight per wave. Pad/overrun slots masked by POSITION to SENTINEL
// before address formation (garbage slot values never become addresses).
#define ACC8(v)                                                                \
    a0 += __uint_as_float((v).x << 16); a1 += __uint_as_float((v).x & 0xffff0000u); \
    a2 += __uint_as_float((v).y << 16); a3 += __uint_as_float((v).y & 0xffff0000u); \
    a4 += __uint_as_float((v).z << 16); a5 += __uint_as_float((v).z & 0xffff0000u); \
    a6 += __uint_as_float((v).w << 16); a7 += __uint_as_float((v).w & 0xffff0000u);

__global__ void sage_layer_kernel(const unsigned short* __restrict__ sorted_src,
                                  const int* __restrict__ prs,
                                  const int* __restrict__ deg,
                                  const float* __restrict__ inv_deg,
                                  const unsigned int* __restrict__ src,
                                  unsigned int* __restrict__ u_out) {
    int gid = blockIdx.x * blockDim.x + threadIdx.x;
    int node = gid >> 6;
    int lane = gid & 63;
    if (node >= N_NODES) return;
    int g = lane >> 4;
    int sub = lane & 15;

    int start = prs[node];
    int dend = start + deg[node];

    float a0 = 0.f, a1 = 0.f, a2 = 0.f, a3 = 0.f;
    float a4 = 0.f, a5 = 0.f, a6 = 0.f, a7 = 0.f;

    const uint4* s4 = reinterpret_cast<const uint4*>(src);
    for (int j = start; j < dend; j += 16) {
        int sl0 = j + g;
        int sl1 = sl0 + 4;
        int sl2 = sl0 + 8;
        int sl3 = sl0 + 12;
        int i0 = sorted_src[sl0];
        int i1 = sorted_src[sl1];
        int i2 = sorted_src[sl2];
        int i3 = sorted_src[sl3];
        if (sl0 >= dend) i0 = SENTINEL;
        if (sl1 >= dend) i1 = SENTINEL;
        if (sl2 >= dend) i2 = SENTINEL;
        if (sl3 >= dend) i3 = SENTINEL;
        uint4 v0 = s4[i0 * 16 + sub];
        uint4 v1 = s4[i1 * 16 + sub];
        uint4 v2 = s4[i2 * 16 + sub];
        uint4 v3 = s4[i3 * 16 + sub];
        ACC8(v0)
        ACC8(v1)
        ACC8(v2)
        ACC8(v3)
    }

    a0 += __shfl_xor(a0, 16); a0 += __shfl_xor(a0, 32);
    a1 += __shfl_xor(a1, 16); a1 += __shfl_xor(a1, 32);
    a2 += __shfl_xor(a2, 16); a2 += __shfl_xor(a2, 32);
    a3 += __shfl_xor(a3, 16); a3 += __shfl_xor(a3, 32);
    a4 += __shfl_xor(a4, 16); a4 += __shfl_xor(a4, 32);
    a5 += __shfl_xor(a5, 16); a5 += __shfl_xor(a5, 32);
    a6 += __shfl_xor(a6, 16); a6 += __shfl_xor(a6, 32);
    a7 += __shfl_xor(a7, 16); a7 += __shfl_xor(a7, 32);

    if (g == 0) {
        float inv = inv_deg[node];
        uint4 w;
        w.x = pack_bf16x2(a0 * inv, a1 * inv);
        w.y = pack_bf16x2(a2 * inv, a3 * inv);
        w.z = pack_bf16x2(a4 * inv, a5 * inv);
        w.w = pack_bf16x2(a6 * inv, a7 * inv);
        reinterpret_cast<uint4*>(u_out)[node * 16 + sub] = w;  // 256 B/row coalesced
    }
}

// ---------------- final combine: res = (17/6)h + 3u1 + 1.5u2 + (1/3)u3 ----------------
__device__ __forceinline__ float blo(unsigned int w) { return __uint_as_float(w << 16); }
__device__ __forceinline__ float bhi(unsigned int w) { return __uint_as_float(w & 0xffff0000u); }

__global__ void combine_kernel(const float* __restrict__ h,
                               const unsigned int* __restrict__ u1b,
                               const unsigned int* __restrict__ u2b,
                               const unsigned int* __restrict__ u3b,
                               float* __restrict__ res) {
    int i = blockIdx.x * blockDim.x + threadIdx.x;  // over N*32 float4s
    if (i >= N_NODES * 32) return;
    float4 hv = reinterpret_cast<const float4*>(h)[i];
    uint2 w1 = reinterpret_cast<const uint2*>(u1b)[i];
    uint2 w2 = reinterpret_cast<const uint2*>(u2b)[i];
    uint2 w3 = reinterpret_cast<const uint2*>(u3b)[i];
    const float C0 = 2.8333333f, C1 = 3.0f, C2 = 1.5f, C3 = 0.33333334f;
    float4 r;
    r.x = C0 * hv.x + C1 * blo(w1.x) + C2 * blo(w2.x) + C3 * blo(w3.x);
    r.y = C0 * hv.y + C1 * bhi(w1.x) + C2 * bhi(w2.x) + C3 * bhi(w3.x);
    r.z = C0 * hv.z + C1 * blo(w1.y) + C2 * blo(w2.y) + C3 * blo(w3.y);
    r.w = C0 * hv.w + C1 * bhi(w1.y) + C2 * bhi(w2.y) + C3 * bhi(w3.y);
    reinterpret_cast<float4*>(res)[i] = r;
}

extern "C" void kernel_launch(void* const* d_in, const int* in_sizes, int n_in,
                              void* d_out, int out_size, void* d_ws, size_t ws_size,
                              hipStream_t stream) {
    const float* h        = (const float*)d_in[0];
    const int*   edge_src = (const int*)d_in[1];
    const int*   edge_dst = (const int*)d_in[2];
    float*       res      = (float*)d_out;

    // Workspace layout (~46.2 MB; >=51.5 MB proven available in round 1):
    char* ws = (char*)d_ws;
    int* deg               = (int*)(ws + 0x000000);   // N ints (200 KB)
    int* bcnt              = (int*)(ws + 0x040000);   // NB ints
    int* prs               = (int*)(ws + 0x042000);   // N+1 ints (200 KB)
    int* partials          = (int*)(ws + 0x074000);   // 256 ints
    float* inv_deg         = (float*)(ws + 0x075000); // N floats (200 KB)
    unsigned short* sorted = (unsigned short*)(ws + 0x0A8000);  // PAD_CAP u16 (2.3 MB)
    unsigned int* bucket   = (unsigned int*)(ws + 0x2E0000);    // NB*BCAP u32 (4.8 MB)
    unsigned int* hb       = (unsigned int*)(ws + 0x0800000);   // (N+1)*64 u32 (12.8 MB)
    unsigned int* u1b      = (unsigned int*)(ws + 0x1500000);   // (N+1)*64 u32
    unsigned int* u2b      = (unsigned int*)(ws + 0x2200000);   // (N+1)*64 u32
    unsigned int* u3b      = hb;  // hb dead after layer 1; reuse for u3

    const int BLK = 256;

    // ---- CSR build: phase A (deg + bucket scatter), scans, phase B (place) ----
    hipMemsetAsync(deg, 0, N_NODES * sizeof(int), stream);
    hipMemsetAsync(bcnt, 0, NB * sizeof(int), stream);
    placeA_kernel<<<(N_EDGES + BLK - 1) / BLK, BLK, 0, stream>>>(
        edge_src, edge_dst, deg, bcnt, bucket);
    scan1_kernel<<<SCAN_BLOCKS, BLK, 0, stream>>>(deg, prs, partials);
    scan2_kernel<<<1, BLK, 0, stream>>>(partials);
    scan3_kernel<<<SCAN_BLOCKS, BLK, 0, stream>>>(prs, partials, deg, inv_deg);
    placeB_kernel<<<NB, BLK, 0, stream>>>(bucket, bcnt, prs, sorted);

    // ---- h -> bf16 (+ zero sentinel rows of hb, u1b, u2b) ----
    convert_kernel<<<((N_NODES + 1) * 64 + BLK - 1) / BLK, BLK, 0, stream>>>(
        h, hb, u1b, u2b);

    // ---- pure gather layers: u1 = M hb, u2 = M u1, u3 = M u2 ----
    const int LGRID = (N_NODES * 64) / BLK;  // 12500 blocks
    sage_layer_kernel<<<LGRID, BLK, 0, stream>>>(sorted, prs, deg, inv_deg, hb, u1b);
    sage_layer_kernel<<<LGRID, BLK, 0, stream>>>(sorted, prs, deg, inv_deg, u1b, u2b);
    sage_layer_kernel<<<LGRID, BLK, 0, stream>>>(sorted, prs, deg, inv_deg, u2b, u3b);

    // ---- res = (17/6)h + 3u1 + 1.5u2 + (1/3)u3 ----
    combine_kernel<<<(N_NODES * 32 + BLK - 1) / BLK, BLK, 0, stream>>>(
        h, u1b, u2b, u3b, res);
}

// Round 6
// 190.409 us; speedup vs baseline: 1.8765x; 1.8765x over previous
//
#include <hip/hip_runtime.h>

#define N_NODES 50000
#define N_EDGES 800000
#define SCAN_BLOCKS 196              // ceil(50000/256)
#define SENTINEL 50000               // zero-row index in gather tables
#define PAD_CAP (N_EDGES + 7 * N_NODES + 32)  // padded slots + slack

// ---------------- degree histogram ----------------
__global__ void hist_kernel(const int* __restrict__ edge_dst,
                            int* __restrict__ deg) {
    int e = blockIdx.x * blockDim.x + threadIdx.x;
    if (e < N_EDGES) atomicAdd(&deg[edge_dst[e]], 1);
}

// ---------------- scan step 1: per-block exclusive scan of PADDED deg ----------------
__global__ void scan1_kernel(const int* __restrict__ deg,
                             int* __restrict__ prs,
                             int* __restrict__ partials) {
    __shared__ int sm[256];
    int tid = threadIdx.x;
    int i = blockIdx.x * 256 + tid;
    int v = (i < N_NODES) ? ((deg[i] + 7) & ~7) : 0;   // pad to multiple of 8
    sm[tid] = v;
    __syncthreads();
    int x = v;
    for (int off = 1; off < 256; off <<= 1) {
        int y = (tid >= off) ? sm[tid - off] : 0;
        __syncthreads();
        x += y;
        sm[tid] = x;
        __syncthreads();
    }
    if (i < N_NODES) prs[i] = x - v;       // exclusive
    if (tid == 255) partials[blockIdx.x] = x;
}

// ---------------- scan step 2: scan block totals (1 block) ----------------
__global__ void scan2_kernel(int* __restrict__ partials) {
    __shared__ int sm[256];
    int tid = threadIdx.x;
    int v = (tid < SCAN_BLOCKS) ? partials[tid] : 0;
    sm[tid] = v;
    __syncthreads();
    int x = v;
    for (int off = 1; off < 256; off <<= 1) {
        int y = (tid >= off) ? sm[tid - off] : 0;
        __syncthreads();
        x += y;
        sm[tid] = x;
        __syncthreads();
    }
    if (tid < SCAN_BLOCKS) partials[tid] = x - v;
}

// ---------------- scan step 3: finalize prs, cursor, inv_deg ----------------
__global__ void scan3_kernel(int* __restrict__ prs,
                             const int* __restrict__ partials,
                             const int* __restrict__ deg,
                             int* __restrict__ cursor,
                             float* __restrict__ inv_deg) {
    int i = blockIdx.x * blockDim.x + threadIdx.x;
    if (i < N_NODES) {
        int rs = prs[i] + partials[i >> 8];
        prs[i] = rs;
        cursor[i] = rs;
        int d = deg[i];
        inv_deg[i] = 1.0f / (float)max(d, 1);
        if (i == N_NODES - 1) prs[N_NODES] = rs + ((d + 7) & ~7);
    }
}

// ---------------- place: counting-sort by dst (known-good round-3 form) ----------------
__global__ void place_kernel(const int* __restrict__ edge_src,
                             const int* __restrict__ edge_dst,
                             int* __restrict__ cursor,
                             unsigned short* __restrict__ sorted_src) {
    int e = blockIdx.x * blockDim.x + threadIdx.x;
    if (e < N_EDGES) {
        int d = edge_dst[e];
        int pos = atomicAdd(&cursor[d], 1);
        sorted_src[pos] = (unsigned short)edge_src[e];
    }
}

// ---------------- bf16x2 pack (RNE) ----------------
__device__ __forceinline__ unsigned int pack_bf16x2(float x, float y) {
    unsigned int bx = __float_as_uint(x);
    unsigned int by = __float_as_uint(y);
    bx = (bx + 0x7fffu + ((bx >> 16) & 1u)) >> 16;
    by = (by + 0x7fffu + ((by >> 16) & 1u)) & 0xffff0000u;
    return (bx & 0xffffu) | by;
}

// ---------------- convert h -> bf16x2; zero sentinel rows ----------------
__global__ void convert_kernel(const float* __restrict__ h,
                               unsigned int* __restrict__ hb,
                               unsigned int* __restrict__ u1b,
                               unsigned int* __restrict__ u2b) {
    int idx = blockIdx.x * blockDim.x + threadIdx.x;  // over (N+1)*64
    if (idx >= (N_NODES + 1) * 64) return;
    if ((idx >> 6) == N_NODES) {
        hb[idx] = 0u;
        u1b[idx] = 0u;
        u2b[idx] = 0u;
    } else {
        float2 v = reinterpret_cast<const float2*>(h)[idx];
        hb[idx] = pack_bf16x2(v.x, v.y);
    }
}

// ---------------- gather layer: 16-lane group per node, 8-deep pipeline ----------------
// Group grp = node; lane sub owns cols [sub*8, sub*8+8). Slot indices come from
// ONE uniform uint2 load per 4 slots. Pad slots masked by POSITION to SENTINEL.
// FINAL: fuse combine -> res = (17/6)h + 3u1 + 1.5u2 + (1/3)*u3_local (f32).
#define ACC8(v)                                                                \
    a0 += __uint_as_float((v).x << 16); a1 += __uint_as_float((v).x & 0xffff0000u); \
    a2 += __uint_as_float((v).y << 16); a3 += __uint_as_float((v).y & 0xffff0000u); \
    a4 += __uint_as_float((v).z << 16); a5 += __uint_as_float((v).z & 0xffff0000u); \
    a6 += __uint_as_float((v).w << 16); a7 += __uint_as_float((v).w & 0xffff0000u);

__device__ __forceinline__ float blo(unsigned int w) { return __uint_as_float(w << 16); }
__device__ __forceinline__ float bhi(unsigned int w) { return __uint_as_float(w & 0xffff0000u); }

template <bool FINAL>
__global__ void sage_layer_kernel(const unsigned short* __restrict__ sorted_src,
                                  const int* __restrict__ prs,
                                  const int* __restrict__ deg,
                                  const float* __restrict__ inv_deg,
                                  const unsigned int* __restrict__ src,
                                  unsigned int* __restrict__ u_out,
                                  const float* __restrict__ h,
                                  const unsigned int* __restrict__ u1t,
                                  const unsigned int* __restrict__ u2t,
                                  float* __restrict__ res) {
    int gid = blockIdx.x * blockDim.x + threadIdx.x;
    int grp = gid >> 4;   // node
    int sub = gid & 15;   // lane within group
    if (grp >= N_NODES) return;

    int start = prs[grp];
    int dend = start + deg[grp];

    float a0 = 0.f, a1 = 0.f, a2 = 0.f, a3 = 0.f;
    float a4 = 0.f, a5 = 0.f, a6 = 0.f, a7 = 0.f;

    const uint4* s4 = reinterpret_cast<const uint4*>(src);
    for (int j = start; j < dend; j += 8) {
        // 2 uniform 8-B index loads cover 8 slots (prs multiples of 8 -> aligned)
        uint2 ss0 = *reinterpret_cast<const uint2*>(sorted_src + j);
        uint2 ss1 = *reinterpret_cast<const uint2*>(sorted_src + j + 4);
        int i0 = ss0.x & 0xffffu, i1 = ss0.x >> 16;
        int i2 = ss0.y & 0xffffu, i3 = ss0.y >> 16;
        int i4 = ss1.x & 0xffffu, i5 = ss1.x >> 16;
        int i6 = ss1.y & 0xffffu, i7 = ss1.y >> 16;
        if (j + 1 >= dend) i1 = SENTINEL;
        if (j + 2 >= dend) i2 = SENTINEL;
        if (j + 3 >= dend) i3 = SENTINEL;
        if (j + 4 >= dend) i4 = SENTINEL;
        if (j + 5 >= dend) i5 = SENTINEL;
        if (j + 6 >= dend) i6 = SENTINEL;
        if (j + 7 >= dend) i7 = SENTINEL;
        uint4 v0 = s4[i0 * 16 + sub];
        uint4 v1 = s4[i1 * 16 + sub];
        uint4 v2 = s4[i2 * 16 + sub];
        uint4 v3 = s4[i3 * 16 + sub];
        uint4 v4 = s4[i4 * 16 + sub];
        uint4 v5 = s4[i5 * 16 + sub];
        uint4 v6 = s4[i6 * 16 + sub];
        uint4 v7 = s4[i7 * 16 + sub];
        ACC8(v0) ACC8(v1) ACC8(v2) ACC8(v3)
        ACC8(v4) ACC8(v5) ACC8(v6) ACC8(v7)
    }

    float inv = inv_deg[grp];
    float u0 = a0 * inv, u1v = a1 * inv, u2v = a2 * inv, u3v = a3 * inv;
    float u4 = a4 * inv, u5v = a5 * inv, u6v = a6 * inv, u7v = a7 * inv;

    if (!FINAL) {
        uint4 w;
        w.x = pack_bf16x2(u0, u1v);
        w.y = pack_bf16x2(u2v, u3v);
        w.z = pack_bf16x2(u4, u5v);
        w.w = pack_bf16x2(u6v, u7v);
        reinterpret_cast<uint4*>(u_out)[grp * 16 + sub] = w;  // 256 B/row coalesced
    } else {
        const float C0 = 2.8333333f, C1 = 3.0f, C2 = 1.5f, C3 = 0.33333334f;
        uint4 w1 = reinterpret_cast<const uint4*>(u1t)[grp * 16 + sub];
        uint4 w2 = reinterpret_cast<const uint4*>(u2t)[grp * 16 + sub];
        int fb = grp * 32 + sub * 2;  // float4 index of lane's first 4 cols
        float4 h0 = reinterpret_cast<const float4*>(h)[fb];
        float4 h1 = reinterpret_cast<const float4*>(h)[fb + 1];
        float4 r0, r1;
        r0.x = C0 * h0.x + C1 * blo(w1.x) + C2 * blo(w2.x) + C3 * u0;
        r0.y = C0 * h0.y + C1 * bhi(w1.x) + C2 * bhi(w2.x) + C3 * u1v;
        r0.z = C0 * h0.z + C1 * blo(w1.y) + C2 * blo(w2.y) + C3 * u2v;
        r0.w = C0 * h0.w + C1 * bhi(w1.y) + C2 * bhi(w2.y) + C3 * u3v;
        r1.x = C0 * h1.x + C1 * blo(w1.z) + C2 * blo(w2.z) + C3 * u4;
        r1.y = C0 * h1.y + C1 * bhi(w1.z) + C2 * bhi(w2.z) + C3 * u5v;
        r1.z = C0 * h1.z + C1 * blo(w1.w) + C2 * blo(w2.w) + C3 * u6v;
        r1.w = C0 * h1.w + C1 * bhi(w1.w) + C2 * bhi(w2.w) + C3 * u7v;
        reinterpret_cast<float4*>(res)[fb] = r0;
        reinterpret_cast<float4*>(res)[fb + 1] = r1;
    }
}

extern "C" void kernel_launch(void* const* d_in, const int* in_sizes, int n_in,
                              void* d_out, int out_size, void* d_ws, size_t ws_size,
                              hipStream_t stream) {
    const float* h        = (const float*)d_in[0];
    const int*   edge_src = (const int*)d_in[1];
    const int*   edge_dst = (const int*)d_in[2];
    float*       res      = (float*)d_out;

    // Workspace layout (~34 MB):
    char* ws = (char*)d_ws;
    int* deg               = (int*)(ws + 0x000000);   // N ints
    int* cursor            = (int*)(ws + 0x040000);   // N ints
    int* prs               = (int*)(ws + 0x080000);   // N+1 ints
    int* partials          = (int*)(ws + 0x0C0000);   // 256 ints
    float* inv_deg         = (float*)(ws + 0x100000); // N floats
    unsigned short* sorted = (unsigned short*)(ws + 0x140000);  // PAD_CAP u16 (2.3 MB)
    unsigned int* hb       = (unsigned int*)(ws + 0x0400000);   // (N+1)*64 u32 (12.8 MB)
    unsigned int* u1b      = (unsigned int*)(ws + 0x1100000);   // (N+1)*64 u32
    unsigned int* u2b      = (unsigned int*)(ws + 0x1E00000);   // (N+1)*64 u32

    const int BLK = 256;

    // ---- CSR build (round-3 known-good form) ----
    hipMemsetAsync(deg, 0, N_NODES * sizeof(int), stream);
    hist_kernel<<<(N_EDGES + BLK - 1) / BLK, BLK, 0, stream>>>(edge_dst, deg);
    scan1_kernel<<<SCAN_BLOCKS, BLK, 0, stream>>>(deg, prs, partials);
    scan2_kernel<<<1, BLK, 0, stream>>>(partials);
    scan3_kernel<<<SCAN_BLOCKS, BLK, 0, stream>>>(prs, partials, deg, cursor, inv_deg);
    place_kernel<<<(N_EDGES + BLK - 1) / BLK, BLK, 0, stream>>>(
        edge_src, edge_dst, cursor, sorted);

    // ---- h -> bf16 (+ zero sentinel rows) ----
    convert_kernel<<<((N_NODES + 1) * 64 + BLK - 1) / BLK, BLK, 0, stream>>>(
        h, hb, u1b, u2b);

    // ---- layers: u1 = M hb, u2 = M u1, final fuses res ----
    const int LGRID = (N_NODES * 16 + BLK - 1) / BLK;  // 3125 blocks
    sage_layer_kernel<false><<<LGRID, BLK, 0, stream>>>(
        sorted, prs, deg, inv_deg, hb, u1b, nullptr, nullptr, nullptr, nullptr);
    sage_layer_kernel<false><<<LGRID, BLK, 0, stream>>>(
        sorted, prs, deg, inv_deg, u1b, u2b, nullptr, nullptr, nullptr, nullptr);
    sage_layer_kernel<true><<<LGRID, BLK, 0, stream>>>(
        sorted, prs, deg, inv_deg, u2b, nullptr, h, u1b, u2b, res);
}